// Round 7
// baseline (71.408 us; speedup 1.0000x reference)
//
#include <hip/hip_runtime.h>
#include <cstdint>

// CovNet BNN: out = clip(x @ sign(W1)^T + b1, ±1) @ W2^T + b2
// B=8192, IN=784, HID=4096, OUT=10.
// R7: m201 phase skeleton + counted vmcnt that NEVER drains in steady state.
// Geometry unchanged from R6 (32x32x16, 24 ds_read_b128/wave/tile).
// Buffers: A ring-2 (2x32KB), B ring-3 (3x32KB) = 160 KiB LDS exactly.
// Per K-tile tt, 4 kk-phases, each {6 ds_read; stage; [vmcnt]; barrier;
// lgkmcnt(0); sched_barrier; 8 MFMA; barrier}:
//   kk0: stage A(tt+1)h0 [2]   kk1: stage A(tt+1)h1 [2]
//   kk2: stage B(tt+2)   [4]   kk3: vmcnt(4)  (tt>=NKT-2: vmcnt(0))
// Ledger at tt/kk3: in-flight [A(tt+1)h0, A(tt+1)h1, B(tt+2)] = 8;
//   vmcnt(4) drains A(tt+1) (+ anything older, e.g. B(tt+1)), leaves B(tt+2)
//   => tile tt+1's reads certified by kk3's vmcnt + barrier. B stays in
//   flight across the tile boundary (no full drain mid-loop).
// Write-after-read: A(tt+1)->buf (tt+1)&1 holds A(tt-1), last read at
//   tt-1/kk3; reads complete before that phase's lgkmcnt(0)+end-barrier,
//   and the stage is issued after it => safe. Same for B slot (tt+2)%3
//   (holds B(tt-1)). Prologue order A(0),B(0),B(1) => vmcnt(4) leaves B(1).

#define BATCH 8192
#define IN_F  784
#define HID   4096
#define OUT_F 10
#define KP    832     // padded K = 13*64
#define NKT   13
#define BM    256
#define BN    256
#define BK    64
#define NCT   (HID / BN)   // 16 col tiles
#define HCS   264          // epilogue hc row stride (f16)

typedef unsigned short u16;
typedef __attribute__((ext_vector_type(4))) unsigned short u16x4;
typedef __attribute__((ext_vector_type(8)))  _Float16 f16x8;
typedef __attribute__((ext_vector_type(4)))  float    f32x4;
typedef __attribute__((ext_vector_type(16))) float    f32x16;

#define BARRIER() do { asm volatile("" ::: "memory"); \
                       __builtin_amdgcn_s_barrier();  \
                       asm volatile("" ::: "memory"); } while (0)
#define WAITV(n)  asm volatile("s_waitcnt vmcnt(" #n ")" ::: "memory")
#define WAITL0()  asm volatile("s_waitcnt lgkmcnt(0)" ::: "memory")

__device__ __forceinline__ u16 f2h(float f) {
  union { _Float16 h; u16 u; } c;
  c.h = (_Float16)f;   // RNE
  return c.u;
}

__device__ __forceinline__ void gl_lds16(const void* g, void* l) {
  __builtin_amdgcn_global_load_lds(
      (const __attribute__((address_space(1))) uint32_t*)g,
      (__attribute__((address_space(3))) uint32_t*)l, 16, 0, 0);
}

// ---------------- prep: x -> f16 (padded), W1 -> sign f16 (padded), W2 -> [16][4096]
__global__ void prep_kernel(const float* __restrict__ x, const float* __restrict__ W1,
                            const float* __restrict__ W2,
                            u16* __restrict__ xh, u16* __restrict__ wh,
                            u16* __restrict__ w2h) {
  const int stride = gridDim.x * blockDim.x;
  const int gid = blockIdx.x * blockDim.x + threadIdx.x;
  const int KP4 = KP / 4;    // 208
  const int IN4 = IN_F / 4;  // 196
  const float4* x4 = (const float4*)x;
  const float4* w4 = (const float4*)W1;
  for (int i = gid; i < BATCH * KP4; i += stride) {
    int b = i / KP4, k = i - b * KP4;
    u16x4 o = {0, 0, 0, 0};
    if (k < IN4) {
      float4 v = x4[(size_t)b * IN4 + k];
      o[0] = f2h(v.x); o[1] = f2h(v.y); o[2] = f2h(v.z); o[3] = f2h(v.w);
    }
    *(u16x4*)&xh[(size_t)b * KP + k * 4] = o;
  }
  for (int i = gid; i < HID * KP4; i += stride) {
    int h = i / KP4, k = i - h * KP4;
    u16x4 o = {0, 0, 0, 0};
    if (k < IN4) {
      float4 v = w4[(size_t)h * IN4 + k];
      o[0] = v.x > 0.f ? 0x3C00 : (v.x < 0.f ? 0xBC00 : 0);
      o[1] = v.y > 0.f ? 0x3C00 : (v.y < 0.f ? 0xBC00 : 0);
      o[2] = v.z > 0.f ? 0x3C00 : (v.z < 0.f ? 0xBC00 : 0);
      o[3] = v.w > 0.f ? 0x3C00 : (v.w < 0.f ? 0xBC00 : 0);
    }
    *(u16x4*)&wh[(size_t)h * KP + k * 4] = o;
  }
  for (int i = gid; i < 16 * HID; i += stride) {
    int o = i >> 12, k = i & (HID - 1);
    w2h[i] = (o < OUT_F) ? f2h(W2[o * HID + k]) : (u16)0;
  }
}

// ---------------- main fused GEMM (256x256, 8 waves, 32x32x16, m201 skeleton)
__global__ void __launch_bounds__(512, 1) gemm_kernel(
    const u16* __restrict__ xh, const u16* __restrict__ wh,
    const u16* __restrict__ w2h, const float* __restrict__ b1,
    float* __restrict__ part) {
  __shared__ union {
    struct { u16 A[2][BM * BK]; u16 B[3][BN * BK]; } m;   // 64+96 = 160 KiB
    struct { u16 hc[128 * HCS]; u16 w2[16 * 256]; } e;    // ~74 KiB
  } sm;

  const int t   = threadIdx.x;
  const int ct  = blockIdx.x;   // col tile (HID), 0..15
  const int br  = blockIdx.y;   // row tile (BATCH), 0..31
  const int w   = t >> 6;       // wave 0..7
  const int l   = t & 63;
  const int wm  = w >> 2;       // 0..1: wave rows = mi*64 + wm*32
  const int wn  = w & 3;        // 0..3: wave cols = nh*128 + wn*32
  const int lo  = l & 31;
  const int hi  = l >> 5;
  const int g   = l >> 4;       // for 16x16 epilogue GEMM2
  const int r16 = l & 15;

  // staging: thread t covers 16B; per 64-row chunk: row = t>>3; source slot
  // pre-swizzled (rule #21): logical slot = (t&7)^(row&7); LDS dest linear.
  const int  srow  = t >> 3;
  const int  sslot = (t & 7) ^ (srow & 7);
  const u16* gA = xh + (size_t)(br * BM) * KP + sslot * 8;
  const u16* gB = wh + (size_t)(ct * BN) * KP + sslot * 8;

  auto stA2 = [&](int tile, int h) {   // A half h: row chunks 2h, 2h+1 (2 ops)
    const int b = tile & 1;
#pragma unroll
    for (int c = 2 * h; c < 2 * h + 2; ++c)
      gl_lds16(gA + (size_t)(c * 64 + srow) * KP + tile * BK,
               &sm.m.A[b][c * 4096 + t * 8]);
  };
  auto stB = [&](int tile, int s) {    // full B tile -> slot s (4 ops)
#pragma unroll
    for (int c = 0; c < 4; ++c)
      gl_lds16(gB + (size_t)(c * 64 + srow) * KP + tile * BK,
               &sm.m.B[s][c * 4096 + t * 8]);
  };
  // read with the same XOR involution: phys slot = logical slot ^ (row&7)
  auto rdA = [&](int p, int mi, int kk) -> f16x8 {
    int row = mi * 64 + wm * 32 + lo;
    return *(const f16x8*)&sm.m.A[p][row * 64 + (((kk * 2 + hi) ^ (row & 7)) << 3)];
  };
  auto rdB = [&](int s, int nh, int kk) -> f16x8 {
    int row = nh * 128 + wn * 32 + lo;
    return *(const f16x8*)&sm.m.B[s][row * 64 + (((kk * 2 + hi) ^ (row & 7)) << 3)];
  };

  f32x16 acc[4][2] = {};   // [mi][nh]

  // prologue: A(0) first, B(0), B(1) last => vmcnt(4) leaves B(1) in flight
  stA2(0, 0); stA2(0, 1);   // 4 ops
  stB(0, 0);                // 4 ops
  stB(1, 1);                // 4 ops
  WAITV(4);                 // A(0), B(0) landed (per-wave)
  BARRIER();                // -> landed chip-wide

  int bs = 0;   // tt % 3
  for (int tt = 0; tt < NKT; ++tt) {
    const int  p      = tt & 1;
    const int  bs2    = (bs >= 1) ? bs - 1 : 2;   // (tt+2) % 3
    const bool a_more = (tt + 1 < NKT);
    const bool b_more = (tt + 2 < NKT);
#pragma unroll
    for (int kk = 0; kk < 4; ++kk) {
      f16x8 af[4], bf[2];
#pragma unroll
      for (int mi = 0; mi < 4; ++mi) af[mi] = rdA(p, mi, kk);
#pragma unroll
      for (int nh = 0; nh < 2; ++nh) bf[nh] = rdB(bs, nh, kk);
      if      (kk == 0) { if (a_more) stA2(tt + 1, 0); }
      else if (kk == 1) { if (a_more) stA2(tt + 1, 1); }
      else if (kk == 2) { if (b_more) stB(tt + 2, bs2); }
      else              { if (tt < NKT - 2) WAITV(4); else WAITV(0); }
      BARRIER();
      WAITL0();                                // own 6 ds_read done
      __builtin_amdgcn_sched_barrier(0);       // rule #18
      __builtin_amdgcn_s_setprio(1);
#pragma unroll
      for (int mi = 0; mi < 4; ++mi)
#pragma unroll
        for (int nh = 0; nh < 2; ++nh)
          acc[mi][nh] = __builtin_amdgcn_mfma_f32_32x32x16_f16(
              af[mi], bf[nh], acc[mi][nh], 0, 0, 0);
      __builtin_amdgcn_s_setprio(0);
      BARRIER();                               // all reads of this phase done
    }
    bs = (bs == 2) ? 0 : bs + 1;
  }

  // ---- epilogue: h = clip(acc + b1), fused GEMM2 through LDS ----
  // Main loop ended with vmcnt(0) at tile NKT-1/kk3 + end barrier; all LDS
  // reads drained (lgkmcnt(0) before final MFMA). e.* overlays m.A/m.B.
  {
    int row = t >> 5, sp = t & 31;
    int ls = (sp & 24) | ((sp ^ row) & 7);   // swizzled logical slot
    gl_lds16(w2h + (size_t)row * HID + ct * BN + ls * 8, &sm.e.w2[t * 8]);
  }
  float b1v[2];
#pragma unroll
  for (int nh = 0; nh < 2; ++nh) b1v[nh] = b1[ct * BN + nh * 128 + wn * 32 + lo];

  float* partBase = part + ((size_t)ct * BATCH + br * BM) * 16;

#pragma unroll
  for (int p = 0; p < 2; ++p) {
    if (p == 1) BARRIER();               // p=0 hc reads done before overwrite
    // pass p writes global rows [p*128, p*128+128) = acc[p*2 + mi'][*]
    // local hc row = mi'*64 + wm*32 + crow;  crow = (r&3)+8*(r>>2)+4*hi
#pragma unroll
    for (int mi = 0; mi < 2; ++mi)
#pragma unroll
      for (int nh = 0; nh < 2; ++nh)
#pragma unroll
        for (int r = 0; r < 16; ++r) {
          float v = acc[p * 2 + mi][nh][r] + b1v[nh];
          v = fminf(fmaxf(v, -1.f), 1.f);
          int crow = (r & 3) + 8 * (r >> 2) + 4 * hi;
          sm.e.hc[(mi * 64 + wm * 32 + crow) * HCS + nh * 128 + wn * 32 + lo] = f2h(v);
        }
    if (p == 0) { WAITV(0); }            // w2 landed
    BARRIER();
    f32x4 acc2 = {};
#pragma unroll
    for (int kk = 0; kk < 8; ++kk) {
      f16x8 a2 = *(const f16x8*)&sm.e.hc[(w * 16 + r16) * HCS + kk * 32 + g * 8];
      int s   = kk * 4 + g;
      int sp2 = (s & 24) | ((s ^ r16) & 7);
      f16x8 b2f = *(const f16x8*)&sm.e.w2[r16 * 256 + sp2 * 8];
      acc2 = __builtin_amdgcn_mfma_f32_16x16x32_f16(a2, b2f, acc2, 0, 0, 0);
    }
#pragma unroll
    for (int r = 0; r < 4; ++r)
      partBase[(size_t)(p * 128 + w * 16 + g * 4 + r) * 16 + r16] = acc2[r];
  }
}

// ---------------- reduce partials over 16 col tiles + b2
__global__ void reduce_kernel(const float* __restrict__ part, const float* __restrict__ b2,
                              float* __restrict__ out) {
  int i = blockIdx.x * blockDim.x + threadIdx.x;
  if (i >= BATCH * OUT_F) return;
  int b = i / OUT_F, o = i - b * OUT_F;
  float acc = b2[o];
#pragma unroll
  for (int c = 0; c < NCT; ++c)
    acc += part[((size_t)c * BATCH + b) * 16 + o];
  out[i] = acc;
}

extern "C" void kernel_launch(void* const* d_in, const int* in_sizes, int n_in,
                              void* d_out, int out_size, void* d_ws, size_t ws_size,
                              hipStream_t stream) {
  const float* x  = (const float*)d_in[0];
  const float* W1 = (const float*)d_in[1];
  const float* b1 = (const float*)d_in[2];
  const float* W2 = (const float*)d_in[3];
  const float* b2 = (const float*)d_in[4];
  float* out = (float*)d_out;

  // ws layout (~29 MB): xh 13.6 MB | wh 6.8 MB | w2h 0.13 MB | part 8.4 MB
  u16* xh  = (u16*)d_ws;
  u16* wh  = xh + (size_t)BATCH * KP;
  u16* w2h = wh + (size_t)HID * KP;
  float* part = (float*)(w2h + 16 * HID);

  hipLaunchKernelGGL(prep_kernel, dim3(2048), dim3(256), 0, stream, x, W1, W2, xh, wh, w2h);
  hipLaunchKernelGGL(gemm_kernel, dim3(NCT, BATCH / BM), dim3(512), 0, stream,
                     xh, wh, w2h, b1, part);
  hipLaunchKernelGGL(reduce_kernel, dim3((BATCH * OUT_F + 255) / 256), dim3(256), 0, stream,
                     part, b2, out);
}

// Round 8
// 63.995 us; speedup vs baseline: 1.1158x; 1.1158x over previous
//
#include <hip/hip_runtime.h>
#include <cstdint>

// CovNet BNN: out = clip(x @ sign(W1)^T + b1, ±1) @ W2^T + b2
// B=8192, IN=784, HID=4096, OUT=10.
// R8: R4 fragment geometry (16x16x32, proven 5.2e5 conflicts) + R7 ring
// buffers/counted-vmcnt + ZERO-re-read kk-phases (24 b128/wave/tile, half of
// m201). Per K-tile: 2 phases (kk=0,1); each reads af[8]+bf[4] ONCE and fires
// 32 independent MFMAs. Only 2 barriers/tile (audit below); ph0 barrier-free.
// Ledger (per wave, steady state at tile t):
//   ph0: 12 ds_read(t,kk0); stage A(t+1)->A[(t+1)&1]   [4 ops]
//        lgkm0; 32 MFMA                                 (no barrier)
//   ph1: 12 ds_read(t,kk1); stage B(t+2)->B[(t+2)%3]   [4 ops]
//        vmcnt(4): outstanding = B(t+1)[4]+A(t+1)[4]+B(t+2)[4]=12 -> clears
//        A(t+1),B(t+1), leaves B(t+2) in flight; BARRIER (chip-wide cert);
//        lgkm0; 32 MFMA; BARRIER (read-drain: gates stA(t+2)@t+1 ph0)
// Write-after-read: stA(t+1) overwrites A(t-1), drained at t-1 ph1 lgkm0 +
//   end-barrier; stB(t+2) overwrites B(t-1), same. Prologue A(0),B(0),B(1):
//   vmcnt(4) clears A(0),B(0), leaves B(1). Tail: t=11 ph1 vmcnt(0); t=12 free.
// Epilogue: R2's verbatim (fused GEMM2 via LDS, passed R2-R7).

#define BATCH 8192
#define IN_F  784
#define HID   4096
#define OUT_F 10
#define KP    832     // padded K = 13*64
#define NKT   13
#define BM    256
#define BN    256
#define BK    64
#define NCT   (HID / BN)   // 16 col tiles
#define HCS   264          // epilogue hc row stride (f16)

typedef unsigned short u16;
typedef __attribute__((ext_vector_type(4))) unsigned short u16x4;
typedef __attribute__((ext_vector_type(8)))  _Float16 f16x8;
typedef __attribute__((ext_vector_type(4)))  float    f32x4;

#define BARRIER() do { asm volatile("" ::: "memory"); \
                       __builtin_amdgcn_s_barrier();  \
                       asm volatile("" ::: "memory"); } while (0)
#define WAITV(n)  asm volatile("s_waitcnt vmcnt(" #n ")" ::: "memory")
#define WAITL0()  asm volatile("s_waitcnt lgkmcnt(0)" ::: "memory")

__device__ __forceinline__ u16 f2h(float f) {
  union { _Float16 h; u16 u; } c;
  c.h = (_Float16)f;   // RNE
  return c.u;
}

__device__ __forceinline__ void gl_lds16(const void* g, void* l) {
  __builtin_amdgcn_global_load_lds(
      (const __attribute__((address_space(1))) uint32_t*)g,
      (__attribute__((address_space(3))) uint32_t*)l, 16, 0, 0);
}

// ---------------- prep: x -> f16 (padded), W1 -> sign f16 (padded), W2 -> [16][4096]
__global__ void prep_kernel(const float* __restrict__ x, const float* __restrict__ W1,
                            const float* __restrict__ W2,
                            u16* __restrict__ xh, u16* __restrict__ wh,
                            u16* __restrict__ w2h) {
  const int stride = gridDim.x * blockDim.x;
  const int gid = blockIdx.x * blockDim.x + threadIdx.x;
  const int KP4 = KP / 4;    // 208
  const int IN4 = IN_F / 4;  // 196
  const float4* x4 = (const float4*)x;
  const float4* w4 = (const float4*)W1;
  for (int i = gid; i < BATCH * KP4; i += stride) {
    int b = i / KP4, k = i - b * KP4;
    u16x4 o = {0, 0, 0, 0};
    if (k < IN4) {
      float4 v = x4[(size_t)b * IN4 + k];
      o[0] = f2h(v.x); o[1] = f2h(v.y); o[2] = f2h(v.z); o[3] = f2h(v.w);
    }
    *(u16x4*)&xh[(size_t)b * KP + k * 4] = o;
  }
  for (int i = gid; i < HID * KP4; i += stride) {
    int h = i / KP4, k = i - h * KP4;
    u16x4 o = {0, 0, 0, 0};
    if (k < IN4) {
      float4 v = w4[(size_t)h * IN4 + k];
      o[0] = v.x > 0.f ? 0x3C00 : (v.x < 0.f ? 0xBC00 : 0);
      o[1] = v.y > 0.f ? 0x3C00 : (v.y < 0.f ? 0xBC00 : 0);
      o[2] = v.z > 0.f ? 0x3C00 : (v.z < 0.f ? 0xBC00 : 0);
      o[3] = v.w > 0.f ? 0x3C00 : (v.w < 0.f ? 0xBC00 : 0);
    }
    *(u16x4*)&wh[(size_t)h * KP + k * 4] = o;
  }
  for (int i = gid; i < 16 * HID; i += stride) {
    int o = i >> 12, k = i & (HID - 1);
    w2h[i] = (o < OUT_F) ? f2h(W2[o * HID + k]) : (u16)0;
  }
}

// ---------------- main fused GEMM (256x256, 8 waves, 16x16x32, 2-phase/tile)
__global__ void __launch_bounds__(512, 1) gemm_kernel(
    const u16* __restrict__ xh, const u16* __restrict__ wh,
    const u16* __restrict__ w2h, const float* __restrict__ b1,
    float* __restrict__ part) {
  __shared__ union {
    struct { u16 A[2][BM * BK]; u16 B[3][BN * BK]; } m;   // 64+96 = 160 KiB
    struct { u16 hc[128 * HCS]; u16 w2[16 * 256]; } e;    // ~74 KiB
  } sm;

  const int t   = threadIdx.x;
  const int ct  = blockIdx.x;   // col tile (HID), 0..15
  const int br  = blockIdx.y;   // row tile (BATCH), 0..31
  const int w   = t >> 6;       // wave 0..7
  const int l   = t & 63;
  const int wm  = w >> 2;       // 0..1: wave rows = wm*128 + mi*16 (mi 0..7)
  const int wn  = w & 3;        // 0..3: wave cols = wn*64  + nj*16 (nj 0..3)
  const int g   = l >> 4;
  const int r16 = l & 15;
  const int swz = (r16 & 7) << 3;   // f16-unit XOR (16B-slot granule)

  // staging: thread t covers 16B; per 64-row chunk: row = t>>3; source slot
  // pre-swizzled (rule #21): logical slot = (t&7)^(row&7); LDS dest linear.
  const int  srow  = t >> 3;
  const int  sslot = (t & 7) ^ (srow & 7);
  const u16* gA = xh + (size_t)(br * BM) * KP + sslot * 8;
  const u16* gB = wh + (size_t)(ct * BN) * KP + sslot * 8;

  auto stA = [&](int tile) {          // full A tile -> ring slot tile&1 (4 ops)
    const int b = tile & 1;
#pragma unroll
    for (int c = 0; c < 4; ++c)
      gl_lds16(gA + (size_t)(c * 64 + srow) * KP + tile * BK,
               &sm.m.A[b][c * 4096 + t * 8]);
  };
  auto stB = [&](int tile, int s) {   // full B tile -> ring slot s (4 ops)
#pragma unroll
    for (int c = 0; c < 4; ++c)
      gl_lds16(gB + (size_t)(c * 64 + srow) * KP + tile * BK,
               &sm.m.B[s][c * 4096 + t * 8]);
  };
  // reads apply the same XOR involution: phys slot = logical slot ^ (row&7)
  auto rdA = [&](int p, int mi, int kk) -> f16x8 {
    int row = wm * 128 + mi * 16 + r16;
    return *(const f16x8*)&sm.m.A[p][row * 64 + ((kk * 32 + g * 8) ^ swz)];
  };
  auto rdB = [&](int s, int nj, int kk) -> f16x8 {
    int row = wn * 64 + nj * 16 + r16;
    return *(const f16x8*)&sm.m.B[s][row * 64 + ((kk * 32 + g * 8) ^ swz)];
  };

  f32x4 acc[8][4] = {};   // [mi][nj]

  // prologue: A(0), B(0) oldest; B(1) stays in flight past the wait
  stA(0);
  stB(0, 0);
  stB(1, 1);
  WAITV(4);
  BARRIER();

  int bs = 0;   // tt % 3
  for (int tt = 0; tt < NKT; ++tt) {
    const int p   = tt & 1;
    const int bs2 = (bs >= 1) ? bs - 1 : 2;   // (tt+2) % 3
    f16x8 af[8], bf[4];

    // ---- ph0 (kk=0): barrier-free ----
#pragma unroll
    for (int mi = 0; mi < 8; ++mi) af[mi] = rdA(p, mi, 0);
#pragma unroll
    for (int nj = 0; nj < 4; ++nj) bf[nj] = rdB(bs, nj, 0);
    if (tt + 1 < NKT) stA(tt + 1);
    WAITL0();
    __builtin_amdgcn_sched_barrier(0);       // rule #18
    __builtin_amdgcn_s_setprio(1);
#pragma unroll
    for (int mi = 0; mi < 8; ++mi)
#pragma unroll
      for (int nj = 0; nj < 4; ++nj)
        acc[mi][nj] = __builtin_amdgcn_mfma_f32_16x16x32_f16(
            af[mi], bf[nj], acc[mi][nj], 0, 0, 0);
    __builtin_amdgcn_s_setprio(0);

    // ---- ph1 (kk=1): counted vmcnt + the tile's 2 barriers ----
#pragma unroll
    for (int mi = 0; mi < 8; ++mi) af[mi] = rdA(p, mi, 1);
#pragma unroll
    for (int nj = 0; nj < 4; ++nj) bf[nj] = rdB(bs, nj, 1);
    if (tt + 2 < NKT) stB(tt + 2, bs2);
    if      (tt < NKT - 2)  { WAITV(4); }    // clears A(t+1),B(t+1); B(t+2) flies
    else if (tt == NKT - 2) { WAITV(0); }    // tail drain
    if (tt < NKT - 1) BARRIER();             // chip-wide cert of tile t+1
    WAITL0();
    __builtin_amdgcn_sched_barrier(0);
    __builtin_amdgcn_s_setprio(1);
#pragma unroll
    for (int mi = 0; mi < 8; ++mi)
#pragma unroll
      for (int nj = 0; nj < 4; ++nj)
        acc[mi][nj] = __builtin_amdgcn_mfma_f32_16x16x32_f16(
            af[mi], bf[nj], acc[mi][nj], 0, 0, 0);
    __builtin_amdgcn_s_setprio(0);
    if (tt < NKT - 1) BARRIER();             // read-drain gate for stA(t+2)

    bs = (bs == 2) ? 0 : bs + 1;
  }

  // ---- epilogue: h = clip(acc + b1), fused GEMM2 through LDS (R2 verbatim) ----
  WAITL0();
  BARRIER();   // all waves' tile-12 reads drained; e.* overlays m.A/m.B
  {
    int row = t >> 5, sp = t & 31;
    int ls = (sp & 24) | ((sp ^ row) & 7);   // swizzled logical slot
    gl_lds16(w2h + (size_t)row * HID + ct * BN + ls * 8, &sm.e.w2[t * 8]);
  }
  float b1v[4];
#pragma unroll
  for (int ni = 0; ni < 4; ++ni) b1v[ni] = b1[ct * BN + wn * 64 + ni * 16 + r16];

  float* partBase = part + ((size_t)ct * BATCH + br * BM) * 16;

#pragma unroll
  for (int p = 0; p < 2; ++p) {
    if (p == 1) BARRIER();               // p=0 hc reads done before overwrite
    if (wm == p) {
#pragma unroll
      for (int mi = 0; mi < 8; ++mi)
#pragma unroll
        for (int ni = 0; ni < 4; ++ni)
#pragma unroll
          for (int r = 0; r < 4; ++r) {
            float v = acc[mi][ni][r] + b1v[ni];
            v = fminf(fmaxf(v, -1.f), 1.f);
            sm.e.hc[(mi * 16 + g * 4 + r) * HCS + wn * 64 + ni * 16 + r16] = f2h(v);
          }
    }
    if (p == 0) { WAITV(0); }            // w2 landed
    BARRIER();
    f32x4 acc2 = {};
#pragma unroll
    for (int kk = 0; kk < 8; ++kk) {
      f16x8 a2 = *(const f16x8*)&sm.e.hc[(w * 16 + r16) * HCS + kk * 32 + g * 8];
      int s   = kk * 4 + g;
      int sp2 = (s & 24) | ((s ^ r16) & 7);
      f16x8 b2f = *(const f16x8*)&sm.e.w2[r16 * 256 + sp2 * 8];
      acc2 = __builtin_amdgcn_mfma_f32_16x16x32_f16(a2, b2f, acc2, 0, 0, 0);
    }
#pragma unroll
    for (int r = 0; r < 4; ++r)
      partBase[(size_t)(p * 128 + w * 16 + g * 4 + r) * 16 + r16] = acc2[r];
  }
}

// ---------------- reduce partials over 16 col tiles + b2
__global__ void reduce_kernel(const float* __restrict__ part, const float* __restrict__ b2,
                              float* __restrict__ out) {
  int i = blockIdx.x * blockDim.x + threadIdx.x;
  if (i >= BATCH * OUT_F) return;
  int b = i / OUT_F, o = i - b * OUT_F;
  float acc = b2[o];
#pragma unroll
  for (int c = 0; c < NCT; ++c)
    acc += part[((size_t)c * BATCH + b) * 16 + o];
  out[i] = acc;
}

extern "C" void kernel_launch(void* const* d_in, const int* in_sizes, int n_in,
                              void* d_out, int out_size, void* d_ws, size_t ws_size,
                              hipStream_t stream) {
  const float* x  = (const float*)d_in[0];
  const float* W1 = (const float*)d_in[1];
  const float* b1 = (const float*)d_in[2];
  const float* W2 = (const float*)d_in[3];
  const float* b2 = (const float*)d_in[4];
  float* out = (float*)d_out;

  // ws layout (~29 MB): xh 13.6 MB | wh 6.8 MB | w2h 0.13 MB | part 8.4 MB
  u16* xh  = (u16*)d_ws;
  u16* wh  = xh + (size_t)BATCH * KP;
  u16* w2h = wh + (size_t)HID * KP;
  float* part = (float*)(w2h + 16 * HID);

  hipLaunchKernelGGL(prep_kernel, dim3(2048), dim3(256), 0, stream, x, W1, W2, xh, wh, w2h);
  hipLaunchKernelGGL(gemm_kernel, dim3(NCT, BATCH / BM), dim3(512), 0, stream,
                     xh, wh, w2h, b1, part);
  hipLaunchKernelGGL(reduce_kernel, dim3((BATCH * OUT_F + 255) / 256), dim3(256), 0, stream,
                     part, b2, out);
}